// Round 10
// baseline (185.534 us; speedup 1.0000x reference)
//
#include <hip/hip_runtime.h>
#include <stdint.h>

// Attention fwd, B=2 H=12 S=2048 D=64, f32 in/out, outputs (out, p_attn).
// R10: R9 base (120.4us) + (1) p-stores WITHOUT the NT hint (fill kernel
// proves 6.9 TB/s through the L2 write path; NT bypasses L2 combining) and
// (2) vectorized out epilogue (LDS transpose through the free bufA, then
// f32x4 stores, 1KB contiguous per wave instr). Everything else = R9.

#define H_HEADS 12
#define S_LEN   2048
#define NKT     32          // S/64 K-tiles
#define L2E     1.4426950408889634f
#define NEGL2E  (-1.4426950408889634e9f)   // -1e9 * log2(e)

typedef _Float16 f16x8 __attribute__((ext_vector_type(8)));
typedef _Float16 f16x4 __attribute__((ext_vector_type(4)));
typedef _Float16 f16x2 __attribute__((ext_vector_type(2)));
typedef float    f32x4 __attribute__((ext_vector_type(4)));

// pack two f32 -> one dword of 2x fp16 (RNE)
static __device__ __forceinline__ unsigned pk(float a, float b) {
    f16x2 t; t[0] = (_Float16)a; t[1] = (_Float16)b;
    return __builtin_bit_cast(unsigned, t);
}

#define MFMA(a, b, c) __builtin_amdgcn_mfma_f32_16x16x32_f16((a), (b), (c), 0, 0, 0)

// Raw barrier: LDS ordering only, no vmcnt drain (stores/loads stay in flight).
#define BAR_LGKM() asm volatile("s_waitcnt lgkmcnt(0)\n\ts_barrier" ::: "memory")

__global__ __launch_bounds__(256, 4)
void attn_fused(const float* __restrict__ Qg, const float* __restrict__ Kg,
                const float* __restrict__ Vg, const int* __restrict__ Mg,
                float* __restrict__ Og, float* __restrict__ Pg)
{
    // bufA: bytes [0,8192) = V tile (B-frag layout, fp16)
    //       bytes [8192,16384) = P staging (fp16, swizzled rows)
    //       epilogue: whole 16 KB = 64x64 f32 out-tile transpose buffer
    __shared__ __align__(16) unsigned short bufA[8192];   // 16 KB
    __shared__ __align__(16) unsigned short KhS[4096];    // 8 KB K tile (fp16, swizzled)
    __shared__ float madd_s[64];                          // 256 B per-tile mask addend

    const int tid  = threadIdx.x;
    const int lane = tid & 63;
    const int w    = tid >> 6;       // wave 0..3 -> q rows [w*16, w*16+16)
    const int l15  = lane & 15;
    const int g    = lane >> 4;      // 0..3

    // XCD swizzle: 768 blocks, 8 XCDs, 96 blocks/XCD = 3 whole heads per XCD
    const int bid = blockIdx.x;
    const int wgs = (bid & 7) * 96 + (bid >> 3);
    const int bh  = wgs >> 5;        // 0..23
    const int qt  = wgs & 31;        // 0..31
    const int b   = bh / H_HEADS;
    const int q0  = qt * 64;

    const size_t headoff = (size_t)bh * (S_LEN * 64);
    const float* Qp = Qg + headoff;
    const float* Kp = Kg + headoff;
    const float* Vp = Vg + headoff;
    const int*   Mp = Mg + b * S_LEN;

    // ---------------- Q A-frags direct from global (x0.125) ----------------
    f16x8 aq[2];
    {
        const float* qrow = Qp + (size_t)(q0 + w * 16 + l15) * 64 + g * 8;
        #pragma unroll
        for (int kk = 0; kk < 2; ++kk) {
            float4 qa = *reinterpret_cast<const float4*>(qrow + kk * 32);
            float4 qb = *reinterpret_cast<const float4*>(qrow + kk * 32 + 4);
            aq[kk][0] = (_Float16)(qa.x * 0.125f); aq[kk][1] = (_Float16)(qa.y * 0.125f);
            aq[kk][2] = (_Float16)(qa.z * 0.125f); aq[kk][3] = (_Float16)(qa.w * 0.125f);
            aq[kk][4] = (_Float16)(qb.x * 0.125f); aq[kk][5] = (_Float16)(qb.y * 0.125f);
            aq[kk][6] = (_Float16)(qb.z * 0.125f); aq[kk][7] = (_Float16)(qb.w * 0.125f);
        }
    }

    float4 kq[4];       // K-tile prefetch registers
    float  vv[16];      // V-tile prefetch registers
    float  mv = 0.f;    // mask prefetch (tid < 64)

    // ================= sweep 1: l = sum over keys of exp(s) =================
    // prologue: load tile 0, write it, issue tile 1
    {
        const float4* src = reinterpret_cast<const float4*>(Kp);
        kq[0] = src[tid]; kq[1] = src[256 + tid]; kq[2] = src[512 + tid]; kq[3] = src[768 + tid];
        if (tid < 64) mv = Mp[tid] ? 0.0f : NEGL2E;
    }
    {
        #pragma unroll
        for (int i = 0; i < 4; ++i) {
            int e = i * 256 + tid, row = e >> 4;
            int byte = (row * 128 + (e & 15) * 8) ^ ((row & 7) << 4);
            float4 v = kq[i];
            *reinterpret_cast<uint2*>(reinterpret_cast<char*>(KhS) + byte) =
                make_uint2(pk(v.x, v.y), pk(v.z, v.w));
        }
        if (tid < 64) madd_s[tid] = mv;
    }
    {
        const float4* src = reinterpret_cast<const float4*>(Kp + 4096);
        kq[0] = src[tid]; kq[1] = src[256 + tid]; kq[2] = src[512 + tid]; kq[3] = src[768 + tid];
        mv = 0.f;
        if (tid < 64) mv = Mp[64 + tid] ? 0.0f : NEGL2E;
    }
    __syncthreads();

    float ls0 = 0.f, ls1 = 0.f, ls2 = 0.f, ls3 = 0.f;
    for (int kt = 0; kt < NKT; ++kt) {
        // ---- compute tile kt from LDS ----
        {
            const int sw = (l15 & 7) << 4;
            #pragma unroll
            for (int ct = 0; ct < 4; ++ct) {
                f32x4 acc = {0.f, 0.f, 0.f, 0.f};
                #pragma unroll
                for (int kk = 0; kk < 2; ++kk) {
                    int byte = ((ct * 16 + l15) * 128 + kk * 64 + g * 16) ^ sw;
                    f16x8 bk = *reinterpret_cast<const f16x8*>(reinterpret_cast<const char*>(KhS) + byte);
                    acc = MFMA(aq[kk], bk, acc);
                }
                float ma = madd_s[ct * 16 + l15];
                ls0 += __builtin_amdgcn_exp2f(__builtin_fmaf(acc[0], L2E, ma));
                ls1 += __builtin_amdgcn_exp2f(__builtin_fmaf(acc[1], L2E, ma));
                ls2 += __builtin_amdgcn_exp2f(__builtin_fmaf(acc[2], L2E, ma));
                ls3 += __builtin_amdgcn_exp2f(__builtin_fmaf(acc[3], L2E, ma));
            }
        }
        BAR_LGKM();        // reads(kt) done; NO vmcnt drain
        if (kt + 1 < NKT) {
            // ---- write tile kt+1 from regs (use-site vmcnt waits on kq) ----
            #pragma unroll
            for (int i = 0; i < 4; ++i) {
                int e = i * 256 + tid, row = e >> 4;
                int byte = (row * 128 + (e & 15) * 8) ^ ((row & 7) << 4);
                float4 v = kq[i];
                *reinterpret_cast<uint2*>(reinterpret_cast<char*>(KhS) + byte) =
                    make_uint2(pk(v.x, v.y), pk(v.z, v.w));
            }
            if (tid < 64) madd_s[tid] = mv;
            BAR_LGKM();    // writes(kt+1) visible
            if (kt + 2 < NKT) {
                // ---- issue loads for tile kt+2 (fly across next compute) ----
                const float4* src = reinterpret_cast<const float4*>(Kp + (size_t)(kt + 2) * 4096);
                kq[0] = src[tid]; kq[1] = src[256 + tid]; kq[2] = src[512 + tid]; kq[3] = src[768 + tid];
                mv = 0.f;
                if (tid < 64) mv = Mp[(kt + 2) * 64 + tid] ? 0.0f : NEGL2E;
            }
        }
    }
    #pragma unroll
    for (int m = 1; m <= 8; m <<= 1) {
        ls0 += __shfl_xor(ls0, m);
        ls1 += __shfl_xor(ls1, m);
        ls2 += __shfl_xor(ls2, m);
        ls3 += __shfl_xor(ls3, m);
    }
    const float li0 = 1.0f / ls0, li1 = 1.0f / ls1, li2 = 1.0f / ls2, li3 = 1.0f / ls3;

    // ================= sweep 2: p = exp(s)/l, PV =================
    f32x4 o0 = {0,0,0,0}, o1 = {0,0,0,0}, o2 = {0,0,0,0}, o3 = {0,0,0,0};
    float* Pout = Pg + ((size_t)bh * S_LEN + q0) * S_LEN;

    // prologue: load tile 0, write it, issue tile 1
    {
        const float4* src = reinterpret_cast<const float4*>(Kp);
        kq[0] = src[tid]; kq[1] = src[256 + tid]; kq[2] = src[512 + tid]; kq[3] = src[768 + tid];
        const float* vsrc  = Vp + (size_t)(w * 8) * 64 + lane;
        const float* vsrc2 = Vp + (size_t)((w + 4) * 8) * 64 + lane;
        #pragma unroll
        for (int j = 0; j < 8; ++j) { vv[j] = vsrc[j * 64]; vv[8 + j] = vsrc2[j * 64]; }
        mv = 0.f;
        if (tid < 64) mv = Mp[tid] ? 0.0f : NEGL2E;
    }
    {
        #pragma unroll
        for (int i = 0; i < 4; ++i) {
            int e = i * 256 + tid, row = e >> 4;
            int byte = (row * 128 + (e & 15) * 8) ^ ((row & 7) << 4);
            float4 v = kq[i];
            *reinterpret_cast<uint2*>(reinterpret_cast<char*>(KhS) + byte) =
                make_uint2(pk(v.x, v.y), pk(v.z, v.w));
        }
        #pragma unroll
        for (int gi = 0; gi < 2; ++gi) {
            int gv = w + gi * 4;
            *reinterpret_cast<uint4*>(reinterpret_cast<char*>(bufA) + (gv * 64 + lane) * 16) =
                make_uint4(pk(vv[gi*8+0], vv[gi*8+1]), pk(vv[gi*8+2], vv[gi*8+3]),
                           pk(vv[gi*8+4], vv[gi*8+5]), pk(vv[gi*8+6], vv[gi*8+7]));
        }
        if (tid < 64) madd_s[tid] = mv;
    }
    {
        const float4* src = reinterpret_cast<const float4*>(Kp + 4096);
        kq[0] = src[tid]; kq[1] = src[256 + tid]; kq[2] = src[512 + tid]; kq[3] = src[768 + tid];
        const float* vsrc  = Vp + (size_t)(64 + w * 8) * 64 + lane;
        const float* vsrc2 = Vp + (size_t)(64 + (w + 4) * 8) * 64 + lane;
        #pragma unroll
        for (int j = 0; j < 8; ++j) { vv[j] = vsrc[j * 64]; vv[8 + j] = vsrc2[j * 64]; }
        mv = 0.f;
        if (tid < 64) mv = Mp[64 + tid] ? 0.0f : NEGL2E;
    }
    __syncthreads();

    for (int kt = 0; kt < NKT; ++kt) {
        // ---- compute tile kt: QK^T, exp, P->PS, PV, vectorized p-stores ----
        {
            const int sw = (l15 & 7) << 4;
            #pragma unroll
            for (int ct = 0; ct < 4; ++ct) {
                f32x4 acc = {0.f, 0.f, 0.f, 0.f};
                #pragma unroll
                for (int kk = 0; kk < 2; ++kk) {
                    int byte = ((ct * 16 + l15) * 128 + kk * 64 + g * 16) ^ sw;
                    f16x8 bk = *reinterpret_cast<const f16x8*>(reinterpret_cast<const char*>(KhS) + byte);
                    acc = MFMA(aq[kk], bk, acc);
                }
                float ma = madd_s[ct * 16 + l15];
                float p0 = __builtin_amdgcn_exp2f(__builtin_fmaf(acc[0], L2E, ma)) * li0;
                float p1 = __builtin_amdgcn_exp2f(__builtin_fmaf(acc[1], L2E, ma)) * li1;
                float p2 = __builtin_amdgcn_exp2f(__builtin_fmaf(acc[2], L2E, ma)) * li2;
                float p3 = __builtin_amdgcn_exp2f(__builtin_fmaf(acc[3], L2E, ma)) * li3;

                // LDS P (fp16, A-fragment layout rows, swizzled) — wave-local
                int pb = 8192 + (w * 16 + g * 4) * 128 + (ct * 16 + l15) * 2;
                *reinterpret_cast<unsigned short*>(reinterpret_cast<char*>(bufA) + ((pb)       ^ (((g * 4 + 0) & 7) << 4))) = __builtin_bit_cast(unsigned short, (_Float16)p0);
                *reinterpret_cast<unsigned short*>(reinterpret_cast<char*>(bufA) + ((pb + 128) ^ (((g * 4 + 1) & 7) << 4))) = __builtin_bit_cast(unsigned short, (_Float16)p1);
                *reinterpret_cast<unsigned short*>(reinterpret_cast<char*>(bufA) + ((pb + 256) ^ (((g * 4 + 2) & 7) << 4))) = __builtin_bit_cast(unsigned short, (_Float16)p2);
                *reinterpret_cast<unsigned short*>(reinterpret_cast<char*>(bufA) + ((pb + 384) ^ (((g * 4 + 3) & 7) << 4))) = __builtin_bit_cast(unsigned short, (_Float16)p3);
            }
            // PV: out += P(16x64) * V(64x64)  (wave-local P; same-wave w->r order)
            #pragma unroll
            for (int kk = 0; kk < 2; ++kk) {
                int abyte = 8192 + (((w * 16 + l15) * 128 + kk * 64 + g * 16) ^ ((l15 & 7) << 4));
                f16x8 ap = *reinterpret_cast<const f16x8*>(reinterpret_cast<const char*>(bufA) + abyte);
                int vb = ((kk * 4 + g) * 64 + l15) * 16;
                f16x8 bv0 = *reinterpret_cast<const f16x8*>(reinterpret_cast<const char*>(bufA) + vb);
                f16x8 bv1 = *reinterpret_cast<const f16x8*>(reinterpret_cast<const char*>(bufA) + vb + 256);
                f16x8 bv2 = *reinterpret_cast<const f16x8*>(reinterpret_cast<const char*>(bufA) + vb + 512);
                f16x8 bv3 = *reinterpret_cast<const f16x8*>(reinterpret_cast<const char*>(bufA) + vb + 768);
                o0 = MFMA(ap, bv0, o0);
                o1 = MFMA(ap, bv1, o1);
                o2 = MFMA(ap, bv2, o2);
                o3 = MFMA(ap, bv3, o3);
            }
            // ---- vectorized p_attn stores (plain, through L2): PS readback -> f32x4 ----
            {
                float* Pbase = Pout + (size_t)(w * 16) * S_LEN + (size_t)kt * 64 + (lane & 15) * 4;
                #pragma unroll
                for (int i = 0; i < 4; ++i) {
                    int rl = i * 4 + (lane >> 4);           // row 0..15 within wave
                    int byte = 8192 + ((((w * 16 + rl) * 128) + (lane & 15) * 8) ^ ((rl & 7) << 4));
                    f16x4 ph = *reinterpret_cast<const f16x4*>(reinterpret_cast<const char*>(bufA) + byte);
                    f32x4 pf = { (float)ph[0], (float)ph[1], (float)ph[2], (float)ph[3] };
                    *reinterpret_cast<f32x4*>(Pbase + (size_t)rl * S_LEN) = pf;
                }
            }
        }
        BAR_LGKM();        // reads(kt) done; NO vmcnt drain (p-stores keep flying)
        if (kt + 1 < NKT) {
            // ---- write tile kt+1 (K, V, mask) from regs ----
            #pragma unroll
            for (int i = 0; i < 4; ++i) {
                int e = i * 256 + tid, row = e >> 4;
                int byte = (row * 128 + (e & 15) * 8) ^ ((row & 7) << 4);
                float4 v = kq[i];
                *reinterpret_cast<uint2*>(reinterpret_cast<char*>(KhS) + byte) =
                    make_uint2(pk(v.x, v.y), pk(v.z, v.w));
            }
            #pragma unroll
            for (int gi = 0; gi < 2; ++gi) {
                int gv = w + gi * 4;
                *reinterpret_cast<uint4*>(reinterpret_cast<char*>(bufA) + (gv * 64 + lane) * 16) =
                    make_uint4(pk(vv[gi*8+0], vv[gi*8+1]), pk(vv[gi*8+2], vv[gi*8+3]),
                               pk(vv[gi*8+4], vv[gi*8+5]), pk(vv[gi*8+6], vv[gi*8+7]));
            }
            if (tid < 64) madd_s[tid] = mv;
            BAR_LGKM();    // writes(kt+1) visible
            if (kt + 2 < NKT) {
                // ---- issue loads for tile kt+2 (fly across next compute) ----
                const float4* src = reinterpret_cast<const float4*>(Kp + (size_t)(kt + 2) * 4096);
                kq[0] = src[tid]; kq[1] = src[256 + tid]; kq[2] = src[512 + tid]; kq[3] = src[768 + tid];
                const float* vsrc  = Vp + (size_t)((kt + 2) * 64 + w * 8) * 64 + lane;
                const float* vsrc2 = Vp + (size_t)((kt + 2) * 64 + (w + 4) * 8) * 64 + lane;
                #pragma unroll
                for (int j = 0; j < 8; ++j) { vv[j] = vsrc[j * 64]; vv[8 + j] = vsrc2[j * 64]; }
                mv = 0.f;
                if (tid < 64) mv = Mp[(kt + 2) * 64 + tid] ? 0.0f : NEGL2E;
            }
        }
    }

    // ---------------- epilogue: out via LDS transpose, f32x4 stores ----------------
    {
        // bufA (16 KB) is free after the last PV; use as 64x64 f32 tile.
        float* ot = reinterpret_cast<float*>(bufA);
        #pragma unroll
        for (int r = 0; r < 4; ++r) {
            int row = w * 16 + g * 4 + r;
            ot[row * 64 + l15 +  0] = o0[r];
            ot[row * 64 + l15 + 16] = o1[r];
            ot[row * 64 + l15 + 32] = o2[r];
            ot[row * 64 + l15 + 48] = o3[r];
        }
        BAR_LGKM();
        float* Ob = Og + headoff + (size_t)q0 * 64;
        #pragma unroll
        for (int i = 0; i < 4; ++i) {
            int cid = i * 256 + tid;          // 1024 f32x4 chunks = 64 rows x 16
            int row = cid >> 4, c = cid & 15;
            f32x4 v = *reinterpret_cast<const f32x4*>(ot + row * 64 + c * 4);
            *reinterpret_cast<f32x4*>(Ob + row * 64 + c * 4) = v;
        }
    }
}

extern "C" void kernel_launch(void* const* d_in, const int* in_sizes, int n_in,
                              void* d_out, int out_size, void* d_ws, size_t ws_size,
                              hipStream_t stream)
{
    (void)in_sizes; (void)n_in; (void)out_size; (void)d_ws; (void)ws_size;
    const float* Q = (const float*)d_in[0];
    const float* K = (const float*)d_in[1];
    const float* V = (const float*)d_in[2];
    const int*   M = (const int*)d_in[3];
    float* Out = (float*)d_out;
    float* P   = Out + (size_t)2 * H_HEADS * S_LEN * 64;   // p_attn after out

    attn_fused<<<dim3(768), 256, 0, stream>>>(Q, K, V, M, Out, P);
}

// Round 11
// 117.828 us; speedup vs baseline: 1.5746x; 1.5746x over previous
//
#include <hip/hip_runtime.h>
#include <stdint.h>

// Attention fwd, B=2 H=12 S=2048 D=64, f32 in/out, outputs (out, p_attn).
// R11: R9 exactly (NT p-stores RESTORED — R10 proved dropping NT costs +65us)
// + the one independent piece of R10 kept: vectorized out epilogue (LDS
// transpose through free bufA, NT f32x4 stores, 1KB contiguous/wave-instr).

#define H_HEADS 12
#define S_LEN   2048
#define NKT     32          // S/64 K-tiles
#define L2E     1.4426950408889634f
#define NEGL2E  (-1.4426950408889634e9f)   // -1e9 * log2(e)

typedef _Float16 f16x8 __attribute__((ext_vector_type(8)));
typedef _Float16 f16x4 __attribute__((ext_vector_type(4)));
typedef _Float16 f16x2 __attribute__((ext_vector_type(2)));
typedef float    f32x4 __attribute__((ext_vector_type(4)));

// pack two f32 -> one dword of 2x fp16 (RNE)
static __device__ __forceinline__ unsigned pk(float a, float b) {
    f16x2 t; t[0] = (_Float16)a; t[1] = (_Float16)b;
    return __builtin_bit_cast(unsigned, t);
}

#define MFMA(a, b, c) __builtin_amdgcn_mfma_f32_16x16x32_f16((a), (b), (c), 0, 0, 0)

// Raw barrier: LDS ordering only, no vmcnt drain (stores/loads stay in flight).
#define BAR_LGKM() asm volatile("s_waitcnt lgkmcnt(0)\n\ts_barrier" ::: "memory")

__global__ __launch_bounds__(256, 4)
void attn_fused(const float* __restrict__ Qg, const float* __restrict__ Kg,
                const float* __restrict__ Vg, const int* __restrict__ Mg,
                float* __restrict__ Og, float* __restrict__ Pg)
{
    // bufA: bytes [0,8192) = V tile (B-frag layout, fp16)
    //       bytes [8192,16384) = P staging (fp16, swizzled rows)
    //       epilogue: whole 16 KB = 64x64 f32 out-tile transpose buffer
    __shared__ __align__(16) unsigned short bufA[8192];   // 16 KB
    __shared__ __align__(16) unsigned short KhS[4096];    // 8 KB K tile (fp16, swizzled)
    __shared__ float madd_s[64];                          // 256 B per-tile mask addend

    const int tid  = threadIdx.x;
    const int lane = tid & 63;
    const int w    = tid >> 6;       // wave 0..3 -> q rows [w*16, w*16+16)
    const int l15  = lane & 15;
    const int g    = lane >> 4;      // 0..3

    // XCD swizzle: 768 blocks, 8 XCDs, 96 blocks/XCD = 3 whole heads per XCD
    const int bid = blockIdx.x;
    const int wgs = (bid & 7) * 96 + (bid >> 3);
    const int bh  = wgs >> 5;        // 0..23
    const int qt  = wgs & 31;        // 0..31
    const int b   = bh / H_HEADS;
    const int q0  = qt * 64;

    const size_t headoff = (size_t)bh * (S_LEN * 64);
    const float* Qp = Qg + headoff;
    const float* Kp = Kg + headoff;
    const float* Vp = Vg + headoff;
    const int*   Mp = Mg + b * S_LEN;

    // ---------------- Q A-frags direct from global (x0.125) ----------------
    f16x8 aq[2];
    {
        const float* qrow = Qp + (size_t)(q0 + w * 16 + l15) * 64 + g * 8;
        #pragma unroll
        for (int kk = 0; kk < 2; ++kk) {
            float4 qa = *reinterpret_cast<const float4*>(qrow + kk * 32);
            float4 qb = *reinterpret_cast<const float4*>(qrow + kk * 32 + 4);
            aq[kk][0] = (_Float16)(qa.x * 0.125f); aq[kk][1] = (_Float16)(qa.y * 0.125f);
            aq[kk][2] = (_Float16)(qa.z * 0.125f); aq[kk][3] = (_Float16)(qa.w * 0.125f);
            aq[kk][4] = (_Float16)(qb.x * 0.125f); aq[kk][5] = (_Float16)(qb.y * 0.125f);
            aq[kk][6] = (_Float16)(qb.z * 0.125f); aq[kk][7] = (_Float16)(qb.w * 0.125f);
        }
    }

    float4 kq[4];       // K-tile prefetch registers
    float  vv[16];      // V-tile prefetch registers
    float  mv = 0.f;    // mask prefetch (tid < 64)

    // ================= sweep 1: l = sum over keys of exp(s) =================
    // prologue: load tile 0, write it, issue tile 1
    {
        const float4* src = reinterpret_cast<const float4*>(Kp);
        kq[0] = src[tid]; kq[1] = src[256 + tid]; kq[2] = src[512 + tid]; kq[3] = src[768 + tid];
        if (tid < 64) mv = Mp[tid] ? 0.0f : NEGL2E;
    }
    {
        #pragma unroll
        for (int i = 0; i < 4; ++i) {
            int e = i * 256 + tid, row = e >> 4;
            int byte = (row * 128 + (e & 15) * 8) ^ ((row & 7) << 4);
            float4 v = kq[i];
            *reinterpret_cast<uint2*>(reinterpret_cast<char*>(KhS) + byte) =
                make_uint2(pk(v.x, v.y), pk(v.z, v.w));
        }
        if (tid < 64) madd_s[tid] = mv;
    }
    {
        const float4* src = reinterpret_cast<const float4*>(Kp + 4096);
        kq[0] = src[tid]; kq[1] = src[256 + tid]; kq[2] = src[512 + tid]; kq[3] = src[768 + tid];
        mv = 0.f;
        if (tid < 64) mv = Mp[64 + tid] ? 0.0f : NEGL2E;
    }
    __syncthreads();

    float ls0 = 0.f, ls1 = 0.f, ls2 = 0.f, ls3 = 0.f;
    for (int kt = 0; kt < NKT; ++kt) {
        // ---- compute tile kt from LDS ----
        {
            const int sw = (l15 & 7) << 4;
            #pragma unroll
            for (int ct = 0; ct < 4; ++ct) {
                f32x4 acc = {0.f, 0.f, 0.f, 0.f};
                #pragma unroll
                for (int kk = 0; kk < 2; ++kk) {
                    int byte = ((ct * 16 + l15) * 128 + kk * 64 + g * 16) ^ sw;
                    f16x8 bk = *reinterpret_cast<const f16x8*>(reinterpret_cast<const char*>(KhS) + byte);
                    acc = MFMA(aq[kk], bk, acc);
                }
                float ma = madd_s[ct * 16 + l15];
                ls0 += __builtin_amdgcn_exp2f(__builtin_fmaf(acc[0], L2E, ma));
                ls1 += __builtin_amdgcn_exp2f(__builtin_fmaf(acc[1], L2E, ma));
                ls2 += __builtin_amdgcn_exp2f(__builtin_fmaf(acc[2], L2E, ma));
                ls3 += __builtin_amdgcn_exp2f(__builtin_fmaf(acc[3], L2E, ma));
            }
        }
        BAR_LGKM();        // reads(kt) done; NO vmcnt drain
        if (kt + 1 < NKT) {
            // ---- write tile kt+1 from regs (use-site vmcnt waits on kq) ----
            #pragma unroll
            for (int i = 0; i < 4; ++i) {
                int e = i * 256 + tid, row = e >> 4;
                int byte = (row * 128 + (e & 15) * 8) ^ ((row & 7) << 4);
                float4 v = kq[i];
                *reinterpret_cast<uint2*>(reinterpret_cast<char*>(KhS) + byte) =
                    make_uint2(pk(v.x, v.y), pk(v.z, v.w));
            }
            if (tid < 64) madd_s[tid] = mv;
            BAR_LGKM();    // writes(kt+1) visible
            if (kt + 2 < NKT) {
                // ---- issue loads for tile kt+2 (fly across next compute) ----
                const float4* src = reinterpret_cast<const float4*>(Kp + (size_t)(kt + 2) * 4096);
                kq[0] = src[tid]; kq[1] = src[256 + tid]; kq[2] = src[512 + tid]; kq[3] = src[768 + tid];
                mv = 0.f;
                if (tid < 64) mv = Mp[(kt + 2) * 64 + tid] ? 0.0f : NEGL2E;
            }
        }
    }
    #pragma unroll
    for (int m = 1; m <= 8; m <<= 1) {
        ls0 += __shfl_xor(ls0, m);
        ls1 += __shfl_xor(ls1, m);
        ls2 += __shfl_xor(ls2, m);
        ls3 += __shfl_xor(ls3, m);
    }
    const float li0 = 1.0f / ls0, li1 = 1.0f / ls1, li2 = 1.0f / ls2, li3 = 1.0f / ls3;

    // ================= sweep 2: p = exp(s)/l, PV =================
    f32x4 o0 = {0,0,0,0}, o1 = {0,0,0,0}, o2 = {0,0,0,0}, o3 = {0,0,0,0};
    float* Pout = Pg + ((size_t)bh * S_LEN + q0) * S_LEN;

    // prologue: load tile 0, write it, issue tile 1
    {
        const float4* src = reinterpret_cast<const float4*>(Kp);
        kq[0] = src[tid]; kq[1] = src[256 + tid]; kq[2] = src[512 + tid]; kq[3] = src[768 + tid];
        const float* vsrc  = Vp + (size_t)(w * 8) * 64 + lane;
        const float* vsrc2 = Vp + (size_t)((w + 4) * 8) * 64 + lane;
        #pragma unroll
        for (int j = 0; j < 8; ++j) { vv[j] = vsrc[j * 64]; vv[8 + j] = vsrc2[j * 64]; }
        mv = 0.f;
        if (tid < 64) mv = Mp[tid] ? 0.0f : NEGL2E;
    }
    {
        #pragma unroll
        for (int i = 0; i < 4; ++i) {
            int e = i * 256 + tid, row = e >> 4;
            int byte = (row * 128 + (e & 15) * 8) ^ ((row & 7) << 4);
            float4 v = kq[i];
            *reinterpret_cast<uint2*>(reinterpret_cast<char*>(KhS) + byte) =
                make_uint2(pk(v.x, v.y), pk(v.z, v.w));
        }
        #pragma unroll
        for (int gi = 0; gi < 2; ++gi) {
            int gv = w + gi * 4;
            *reinterpret_cast<uint4*>(reinterpret_cast<char*>(bufA) + (gv * 64 + lane) * 16) =
                make_uint4(pk(vv[gi*8+0], vv[gi*8+1]), pk(vv[gi*8+2], vv[gi*8+3]),
                           pk(vv[gi*8+4], vv[gi*8+5]), pk(vv[gi*8+6], vv[gi*8+7]));
        }
        if (tid < 64) madd_s[tid] = mv;
    }
    {
        const float4* src = reinterpret_cast<const float4*>(Kp + 4096);
        kq[0] = src[tid]; kq[1] = src[256 + tid]; kq[2] = src[512 + tid]; kq[3] = src[768 + tid];
        const float* vsrc  = Vp + (size_t)(64 + w * 8) * 64 + lane;
        const float* vsrc2 = Vp + (size_t)(64 + (w + 4) * 8) * 64 + lane;
        #pragma unroll
        for (int j = 0; j < 8; ++j) { vv[j] = vsrc[j * 64]; vv[8 + j] = vsrc2[j * 64]; }
        mv = 0.f;
        if (tid < 64) mv = Mp[64 + tid] ? 0.0f : NEGL2E;
    }
    __syncthreads();

    for (int kt = 0; kt < NKT; ++kt) {
        // ---- compute tile kt: QK^T, exp, P->PS, PV, vectorized NT p-stores ----
        {
            const int sw = (l15 & 7) << 4;
            #pragma unroll
            for (int ct = 0; ct < 4; ++ct) {
                f32x4 acc = {0.f, 0.f, 0.f, 0.f};
                #pragma unroll
                for (int kk = 0; kk < 2; ++kk) {
                    int byte = ((ct * 16 + l15) * 128 + kk * 64 + g * 16) ^ sw;
                    f16x8 bk = *reinterpret_cast<const f16x8*>(reinterpret_cast<const char*>(KhS) + byte);
                    acc = MFMA(aq[kk], bk, acc);
                }
                float ma = madd_s[ct * 16 + l15];
                float p0 = __builtin_amdgcn_exp2f(__builtin_fmaf(acc[0], L2E, ma)) * li0;
                float p1 = __builtin_amdgcn_exp2f(__builtin_fmaf(acc[1], L2E, ma)) * li1;
                float p2 = __builtin_amdgcn_exp2f(__builtin_fmaf(acc[2], L2E, ma)) * li2;
                float p3 = __builtin_amdgcn_exp2f(__builtin_fmaf(acc[3], L2E, ma)) * li3;

                // LDS P (fp16, A-fragment layout rows, swizzled) — wave-local
                int pb = 8192 + (w * 16 + g * 4) * 128 + (ct * 16 + l15) * 2;
                *reinterpret_cast<unsigned short*>(reinterpret_cast<char*>(bufA) + ((pb)       ^ (((g * 4 + 0) & 7) << 4))) = __builtin_bit_cast(unsigned short, (_Float16)p0);
                *reinterpret_cast<unsigned short*>(reinterpret_cast<char*>(bufA) + ((pb + 128) ^ (((g * 4 + 1) & 7) << 4))) = __builtin_bit_cast(unsigned short, (_Float16)p1);
                *reinterpret_cast<unsigned short*>(reinterpret_cast<char*>(bufA) + ((pb + 256) ^ (((g * 4 + 2) & 7) << 4))) = __builtin_bit_cast(unsigned short, (_Float16)p2);
                *reinterpret_cast<unsigned short*>(reinterpret_cast<char*>(bufA) + ((pb + 384) ^ (((g * 4 + 3) & 7) << 4))) = __builtin_bit_cast(unsigned short, (_Float16)p3);
            }
            // PV: out += P(16x64) * V(64x64)  (wave-local P; same-wave w->r order)
            #pragma unroll
            for (int kk = 0; kk < 2; ++kk) {
                int abyte = 8192 + (((w * 16 + l15) * 128 + kk * 64 + g * 16) ^ ((l15 & 7) << 4));
                f16x8 ap = *reinterpret_cast<const f16x8*>(reinterpret_cast<const char*>(bufA) + abyte);
                int vb = ((kk * 4 + g) * 64 + l15) * 16;
                f16x8 bv0 = *reinterpret_cast<const f16x8*>(reinterpret_cast<const char*>(bufA) + vb);
                f16x8 bv1 = *reinterpret_cast<const f16x8*>(reinterpret_cast<const char*>(bufA) + vb + 256);
                f16x8 bv2 = *reinterpret_cast<const f16x8*>(reinterpret_cast<const char*>(bufA) + vb + 512);
                f16x8 bv3 = *reinterpret_cast<const f16x8*>(reinterpret_cast<const char*>(bufA) + vb + 768);
                o0 = MFMA(ap, bv0, o0);
                o1 = MFMA(ap, bv1, o1);
                o2 = MFMA(ap, bv2, o2);
                o3 = MFMA(ap, bv3, o3);
            }
            // ---- vectorized NT p_attn stores: PS readback (fp16) -> f32x4 ----
            // lanes 0-15 cover one row: 16 lanes x 16B = 256B contiguous
            {
                float* Pbase = Pout + (size_t)(w * 16) * S_LEN + (size_t)kt * 64 + (lane & 15) * 4;
                #pragma unroll
                for (int i = 0; i < 4; ++i) {
                    int rl = i * 4 + (lane >> 4);           // row 0..15 within wave
                    int byte = 8192 + ((((w * 16 + rl) * 128) + (lane & 15) * 8) ^ ((rl & 7) << 4));
                    f16x4 ph = *reinterpret_cast<const f16x4*>(reinterpret_cast<const char*>(bufA) + byte);
                    f32x4 pf = { (float)ph[0], (float)ph[1], (float)ph[2], (float)ph[3] };
                    __builtin_nontemporal_store(pf, reinterpret_cast<f32x4*>(Pbase + (size_t)rl * S_LEN));
                }
            }
        }
        BAR_LGKM();        // reads(kt) done; NO vmcnt drain (p-stores keep flying)
        if (kt + 1 < NKT) {
            // ---- write tile kt+1 (K, V, mask) from regs ----
            #pragma unroll
            for (int i = 0; i < 4; ++i) {
                int e = i * 256 + tid, row = e >> 4;
                int byte = (row * 128 + (e & 15) * 8) ^ ((row & 7) << 4);
                float4 v = kq[i];
                *reinterpret_cast<uint2*>(reinterpret_cast<char*>(KhS) + byte) =
                    make_uint2(pk(v.x, v.y), pk(v.z, v.w));
            }
            #pragma unroll
            for (int gi = 0; gi < 2; ++gi) {
                int gv = w + gi * 4;
                *reinterpret_cast<uint4*>(reinterpret_cast<char*>(bufA) + (gv * 64 + lane) * 16) =
                    make_uint4(pk(vv[gi*8+0], vv[gi*8+1]), pk(vv[gi*8+2], vv[gi*8+3]),
                               pk(vv[gi*8+4], vv[gi*8+5]), pk(vv[gi*8+6], vv[gi*8+7]));
            }
            if (tid < 64) madd_s[tid] = mv;
            BAR_LGKM();    // writes(kt+1) visible
            if (kt + 2 < NKT) {
                // ---- issue loads for tile kt+2 (fly across next compute) ----
                const float4* src = reinterpret_cast<const float4*>(Kp + (size_t)(kt + 2) * 4096);
                kq[0] = src[tid]; kq[1] = src[256 + tid]; kq[2] = src[512 + tid]; kq[3] = src[768 + tid];
                const float* vsrc  = Vp + (size_t)((kt + 2) * 64 + w * 8) * 64 + lane;
                const float* vsrc2 = Vp + (size_t)((kt + 2) * 64 + (w + 4) * 8) * 64 + lane;
                #pragma unroll
                for (int j = 0; j < 8; ++j) { vv[j] = vsrc[j * 64]; vv[8 + j] = vsrc2[j * 64]; }
                mv = 0.f;
                if (tid < 64) mv = Mp[(kt + 2) * 64 + tid] ? 0.0f : NEGL2E;
            }
        }
    }

    // ---------------- epilogue: out via LDS transpose, NT f32x4 stores ----------------
    {
        // bufA (16 KB) is free after the last PV; use as 64x64 f32 tile.
        float* ot = reinterpret_cast<float*>(bufA);
        #pragma unroll
        for (int r = 0; r < 4; ++r) {
            int row = w * 16 + g * 4 + r;
            ot[row * 64 + l15 +  0] = o0[r];
            ot[row * 64 + l15 + 16] = o1[r];
            ot[row * 64 + l15 + 32] = o2[r];
            ot[row * 64 + l15 + 48] = o3[r];
        }
        BAR_LGKM();
        float* Ob = Og + headoff + (size_t)q0 * 64;
        #pragma unroll
        for (int i = 0; i < 4; ++i) {
            int cid = i * 256 + tid;          // 1024 f32x4 chunks = 64 rows x 16
            int row = cid >> 4, c = cid & 15;
            f32x4 v = *reinterpret_cast<const f32x4*>(ot + row * 64 + c * 4);
            __builtin_nontemporal_store(v, reinterpret_cast<f32x4*>(Ob + row * 64 + c * 4));
        }
    }
}

extern "C" void kernel_launch(void* const* d_in, const int* in_sizes, int n_in,
                              void* d_out, int out_size, void* d_ws, size_t ws_size,
                              hipStream_t stream)
{
    (void)in_sizes; (void)n_in; (void)out_size; (void)d_ws; (void)ws_size;
    const float* Q = (const float*)d_in[0];
    const float* K = (const float*)d_in[1];
    const float* V = (const float*)d_in[2];
    const int*   M = (const int*)d_in[3];
    float* Out = (float*)d_out;
    float* P   = Out + (size_t)2 * H_HEADS * S_LEN * 64;   // p_attn after out

    attn_fused<<<dim3(768), 256, 0, stream>>>(Q, K, V, M, Out, P);
}